// Round 13
// baseline (216.464 us; speedup 1.0000x reference)
//
#include <hip/hip_runtime.h>
#include <hip/hip_bf16.h>
#include <cstdint>

#define BB 64
#define NN 512
#define MM 1024
#define DD 128

typedef __bf16 bf16x8 __attribute__((ext_vector_type(8)));
typedef float f32x4 __attribute__((ext_vector_type(4)));

static __device__ __forceinline__ unsigned short f2bf(float f) {
    union { float f; unsigned int i; } v; v.f = f;
    unsigned int x = v.i;
    x += 0x7FFFu + ((x >> 16) & 1u);   // RNE
    return (unsigned short)(x >> 16);
}
// packed v_cvt_pk_bf16_f32: low = a, high = b
static __device__ __forceinline__ unsigned int f2bf2(float a, float b) {
    union { __hip_bfloat162 h; unsigned int u; } c;
    c.h = __float22bfloat162_rn(make_float2(a, b));
    return c.u;
}

// ---------- Kernel 1: Vp = relu(h_p @ Wv^T + b)  (r10-proven) ----------------
// Grid 1024, 4 blocks/CU. Outputs: Vp tiles [b][mt][64][128], VpT tiles
// [b][mt][128][64], all stores coalesced uint4 via LDS.
__global__ __launch_bounds__(256, 4) void proj_v_kernel(
    const float* __restrict__ X,
    const float* __restrict__ Wv,
    const float* __restrict__ bias,
    unsigned short* __restrict__ Y,
    unsigned short* __restrict__ YT)
{
    __shared__ __align__(16) unsigned short Ws[128 * 136];   // 34816 B, reused
    unsigned short* Ys = Ws;            // 64*128 shorts
    unsigned short* Ts = Ws + 8192;     // 128*72 shorts
    const int t = threadIdx.x;
    const int lane = t & 63;
    const int wave = t >> 6;
    const int n16 = lane & 15, q = lane >> 4;
    const long row0 = (long)blockIdx.x * 64;

    // X loads FIRST (latency overlaps W staging below)
    float4 xv[8];
    {
        const float* xrow = X + (row0 + wave * 16 + n16) * DD + q * 8;
        #pragma unroll
        for (int kk = 0; kk < 4; ++kk) {
            xv[2 * kk]     = *(const float4*)(xrow + kk * 32);
            xv[2 * kk + 1] = *(const float4*)(xrow + kk * 32 + 4);
        }
    }

    // stage Wv fp32 -> bf16 into padded LDS
    {
        const float4* Wg = (const float4*)Wv;
        #pragma unroll
        for (int i = 0; i < 16; ++i) {
            int idx = i * 256 + t;            // 4096 float4
            float4 v = Wg[idx];
            int off = idx * 4;                // shorts
            uint2 u = { f2bf2(v.x, v.y), f2bf2(v.z, v.w) };
            *(uint2*)&Ws[(off >> 7) * 136 + (off & 127)] = u;
        }
    }
    __syncthreads();

    f32x4 acc[8];
    #pragma unroll
    for (int j = 0; j < 8; ++j) acc[j] = {0.f, 0.f, 0.f, 0.f};

    #pragma unroll
    for (int kk = 0; kk < 4; ++kk) {
        float4 x0 = xv[2 * kk], x1 = xv[2 * kk + 1];
        union { bf16x8 v; unsigned int u[4]; } a;
        a.u[0] = f2bf2(x0.x, x0.y); a.u[1] = f2bf2(x0.z, x0.w);
        a.u[2] = f2bf2(x1.x, x1.y); a.u[3] = f2bf2(x1.z, x1.w);
        #pragma unroll
        for (int j = 0; j < 8; ++j) {
            bf16x8 b = *(const bf16x8*)&Ws[(j * 16 + n16) * 136 + q * 8 + kk * 32];
            acc[j] = __builtin_amdgcn_mfma_f32_16x16x32_bf16(a.v, b, acc[j], 0, 0, 0);
        }
    }

    unsigned short yb[8][4];
    #pragma unroll
    for (int j = 0; j < 8; ++j) {
        const float bv = bias[j * 16 + n16];
        float y[4];
        #pragma unroll
        for (int r = 0; r < 4; ++r) {
            float v = acc[j][r] + bv;
            y[r] = v > 0.f ? v : 0.f;
        }
        uint2 u = { f2bf2(y[0], y[1]), f2bf2(y[2], y[3]) };
        *(uint2*)&yb[j][0] = u;
    }
    __syncthreads();   // Ws reads done; reuse as Ys/Ts

    #pragma unroll
    for (int j = 0; j < 8; ++j) {
        const int e = j * 16 + n16;
        #pragma unroll
        for (int r = 0; r < 4; ++r)
            Ys[(wave * 16 + q * 4 + r) * 128 + e] = yb[j][r];
        *(uint2*)&Ts[e * 72 + wave * 16 + q * 4] = *(uint2*)&yb[j][0];
    }
    __syncthreads();

    {
        uint4* dstY = (uint4*)(Y + row0 * DD);
        const long b = row0 >> 10;
        const long mt = (row0 & 1023) >> 6;
        uint4* dstT = (uint4*)(YT + ((b * 16 + mt) * 128) * 64);
        #pragma unroll
        for (int i = 0; i < 4; ++i) {
            int idx = i * 256 + t;
            dstY[idx] = ((const uint4*)Ys)[idx];
            int e = idx >> 3, m = (idx & 7) * 8;
            dstT[idx] = *(const uint4*)&Ts[e * 72 + m];
        }
    }
}

// ---------- Kernel 2: fused proj_c + BARRIER-FREE flash attention ------------
// Grid 512 = (b, nt); 4 waves x 16 n (n-split). Phase 1: r10-proven Uc
// (Wu staged in LDS, Ucs pre-scaled by log2 e). Flash loop: QK A-frags and
// PV B-frags read DIRECTLY from global (tiled Vp/VpT, 16B per lane, L2-hot
// from proj_v on the same XCD); Ps wave-private LDS; ZERO barriers in the
// loop -> no vmcnt(0) barrier drains, waves free-run.
__global__ __launch_bounds__(256, 2) void attn_kernel(
    const float* __restrict__ hc,             // (B*512,128) fp32
    const float* __restrict__ Wu,             // (128,128) fp32
    const float* __restrict__ Ub,             // (128) fp32
    const unsigned short* __restrict__ Vp,    // (B,16,64,128) bf16 tiled
    const unsigned short* __restrict__ VpT,   // (B,16,128,64) bf16 tiled
    float* __restrict__ part)                 // (B*8,128) fp32
{
    // shorts. Phase1: Ws[0,17408) Ucs[17408,26112).
    // Loop: Ps[0,4608) (aliases dead Ws; 4 waves x 16 x 72).
    // Epilogue: red = floats at short-offset 4608 (512 floats).
    __shared__ __align__(16) unsigned short smem[26112];
    unsigned short* Ws  = smem;
    unsigned short* Ucs = smem + 17408;
    unsigned short* Ps  = smem;

    const int t = threadIdx.x;
    const int lane = t & 63;
    const int wave = t >> 6;
    const int n16 = lane & 15, q = lane >> 4;

    const int id = blockIdx.x;
    const int xcd = id & 7;
    const int slot = id >> 3;
    const int b = xcd * 8 + (slot >> 3);
    const int nt = slot & 7;

    const unsigned short* vpb = Vp + (long)b * MM * DD;    // 16 tiles of 8192
    const unsigned short* vtb = VpT + (long)b * MM * DD;

    const float LOG2E = 1.44269504088896f;

    // ---- Phase 1: Uc for this block's 64 n-rows (r10-proven) ----
    {
        const float4* Wg = (const float4*)Wu;
        #pragma unroll
        for (int i = 0; i < 16; ++i) {
            int idx = i * 256 + t;
            float4 v = Wg[idx];
            int off = idx * 4;
            uint2 u = { f2bf2(v.x, v.y), f2bf2(v.z, v.w) };
            *(uint2*)&Ws[(off >> 7) * 136 + (off & 127)] = u;
        }
    }
    __syncthreads();

    f32x4 acc[8];
    #pragma unroll
    for (int j = 0; j < 8; ++j) acc[j] = {0.f, 0.f, 0.f, 0.f};
    {
        const float* xrow = hc + ((long)b * NN + nt * 64 + wave * 16 + n16) * DD + q * 8;
        #pragma unroll
        for (int kk = 0; kk < 4; ++kk) {
            float4 x0 = *(const float4*)(xrow + kk * 32);
            float4 x1 = *(const float4*)(xrow + kk * 32 + 4);
            union { bf16x8 v; unsigned int u[4]; } a;
            a.u[0] = f2bf2(x0.x, x0.y); a.u[1] = f2bf2(x0.z, x0.w);
            a.u[2] = f2bf2(x1.x, x1.y); a.u[3] = f2bf2(x1.z, x1.w);
            #pragma unroll
            for (int j = 0; j < 8; ++j) {
                bf16x8 bb = *(const bf16x8*)&Ws[(j * 16 + n16) * 136 + q * 8 + kk * 32];
                acc[j] = __builtin_amdgcn_mfma_f32_16x16x32_bf16(a.v, bb, acc[j], 0, 0, 0);
            }
        }
    }
    float ucred[8];
    #pragma unroll
    for (int j = 0; j < 8; ++j) {
        const float bv = Ub[j * 16 + n16];
        float s = 0.f;
        #pragma unroll
        for (int r = 0; r < 4; ++r) {
            float v = acc[j][r] + bv;
            v = v > 0.f ? v : 0.f;
            s += v;
            // store Uc * log2(e): QK output feeds exp2 directly
            Ucs[(wave * 16 + q * 4 + r) * 136 + j * 16 + n16] = f2bf(v * LOG2E);
        }
        ucred[j] = s;
    }
    __syncthreads();     // Ucs ready; Ws reads done (Ps alias of Ws now safe)

    // This wave's OWN 16 n-rows as QK B-frags (n-split, r9-proven)
    bf16x8 Bg[4];
    #pragma unroll
    for (int kk = 0; kk < 4; ++kk)
        Bg[kk] = *(const bf16x8*)&Ucs[(wave * 16 + n16) * 136 + q * 8 + kk * 32];

    f32x4 O[8];
    #pragma unroll
    for (int j = 0; j < 8; ++j) O[j] = {0.f, 0.f, 0.f, 0.f};
    float lpart = 0.f;

    // ---- Flash loop: NO barriers. Operands stream from L2 (global). ----
    for (int mt = 0; mt < 16; ++mt) {
        const unsigned short* vpt_ = vpb + mt * 8192;   // [64 m][128 d]
        const unsigned short* vtt_ = vtb + mt * 8192;   // [128 d][64 m]

        // S^T = Vp_tile * Uc^T : S[j] reg r -> m = j*16+q*4+r, n = wave*16+n16
        f32x4 S[4];
        #pragma unroll
        for (int j = 0; j < 4; ++j) S[j] = {0.f, 0.f, 0.f, 0.f};
        #pragma unroll
        for (int kk = 0; kk < 4; ++kk) {
            #pragma unroll
            for (int j = 0; j < 4; ++j) {
                bf16x8 a = *(const bf16x8*)&vpt_[(j * 16 + n16) * 128 + kk * 32 + q * 8];
                S[j] = __builtin_amdgcn_mfma_f32_16x16x32_bf16(a, Bg[kk], S[j], 0, 0, 0);
            }
        }

        // p = exp2(S) (Uc pre-scaled); Ps wave-private
        #pragma unroll
        for (int j = 0; j < 4; ++j) {
            float p0 = __builtin_exp2f(S[j][0]);
            float p1 = __builtin_exp2f(S[j][1]);
            float p2 = __builtin_exp2f(S[j][2]);
            float p3 = __builtin_exp2f(S[j][3]);
            lpart += (p0 + p1) + (p2 + p3);
            uint2 u = { f2bf2(p0, p1), f2bf2(p2, p3) };
            *(uint2*)&Ps[wave * 1152 + n16 * 72 + j * 16 + q * 4] = u;
        }

        // O += P * V : A = Ps rows (own n, k=m), B = VpT rows (d, k=m) global
        #pragma unroll
        for (int kk = 0; kk < 2; ++kk) {
            bf16x8 a = *(const bf16x8*)&Ps[wave * 1152 + n16 * 72 + kk * 32 + q * 8];
            #pragma unroll
            for (int j = 0; j < 8; ++j) {
                bf16x8 bb = *(const bf16x8*)&vtt_[(j * 16 + n16) * 64 + kk * 32 + q * 8];
                O[j] = __builtin_amdgcn_mfma_f32_16x16x32_bf16(a, bb, O[j], 0, 0, 0);
            }
        }
    }

    // ---- epilogue (r9-proven): l per own-n, divide, cross-wave reduce ----
    lpart += __shfl_xor(lpart, 16);
    lpart += __shfl_xor(lpart, 32);

    float inv[4];
    #pragma unroll
    for (int r = 0; r < 4; ++r)
        inv[r] = 1.0f / __shfl(lpart, q * 4 + r);

    float* red = (float*)(smem + 4608);     // 512 floats, disjoint from all Ps
    #pragma unroll
    for (int j = 0; j < 8; ++j) {
        float s = ucred[j]
                + O[j][0] * inv[0] + O[j][1] * inv[1]
                + O[j][2] * inv[2] + O[j][3] * inv[3];
        s += __shfl_xor(s, 16);
        s += __shfl_xor(s, 32);
        if (q == 0)
            red[wave * 128 + j * 16 + n16] = s;
    }
    __syncthreads();
    if (t < 128) {
        float tot = red[t] + red[128 + t] + red[256 + t] + red[384 + t];
        part[(long)(b * 8 + nt) * DD + t] = tot;
    }
}

// ---------- Kernel 3: out[b][d] = (Sigma_nt part) * q[d] / N -----------------
__global__ __launch_bounds__(256) void finalize_kernel(
    const float* __restrict__ part, const float* __restrict__ qv,
    float* __restrict__ out)
{
    int i = blockIdx.x * 256 + threadIdx.x;     // 8192
    int b = i >> 7, d = i & 127;
    const float* p = part + (long)b * 8 * DD + d;
    float s = 0.f;
    #pragma unroll
    for (int nt = 0; nt < 8; ++nt) s += p[nt * DD];
    out[i] = s * qv[d] * (1.0f / (float)NN);
}

extern "C" void kernel_launch(void* const* d_in, const int* in_sizes, int n_in,
                              void* d_out, int out_size, void* d_ws, size_t ws_size,
                              hipStream_t stream) {
    const float* h_c = (const float*)d_in[0];
    const float* h_p = (const float*)d_in[1];
    const float* U_w = (const float*)d_in[2];
    const float* U_b = (const float*)d_in[3];
    const float* V_w = (const float*)d_in[4];
    const float* V_b = (const float*)d_in[5];
    const float* qv  = (const float*)d_in[6];
    float* out = (float*)d_out;

    unsigned short* Vp  = (unsigned short*)d_ws;                 // (B,16,64,128) bf16
    unsigned short* VpT = Vp + (size_t)BB * MM * DD;             // (B,16,128,64) bf16
    float* part = (float*)(VpT + (size_t)BB * MM * DD);          // (B*8,128) fp32

    proj_v_kernel<<<BB * MM / 64, 256, 0, stream>>>(h_p, V_w, V_b, Vp, VpT);
    attn_kernel<<<512, 256, 0, stream>>>(h_c, U_w, U_b, Vp, VpT, part);
    finalize_kernel<<<32, 256, 0, stream>>>(part, qv, out);
}

// Round 14
// 133.126 us; speedup vs baseline: 1.6260x; 1.6260x over previous
//
#include <hip/hip_runtime.h>
#include <hip/hip_bf16.h>
#include <cstdint>

#define BB 64
#define NN 512
#define MM 1024
#define DD 128

typedef __bf16 bf16x8 __attribute__((ext_vector_type(8)));
typedef float f32x4 __attribute__((ext_vector_type(4)));

static __device__ __forceinline__ unsigned short f2bf(float f) {
    union { float f; unsigned int i; } v; v.f = f;
    unsigned int x = v.i;
    x += 0x7FFFu + ((x >> 16) & 1u);   // RNE
    return (unsigned short)(x >> 16);
}
// packed v_cvt_pk_bf16_f32: low = a, high = b
static __device__ __forceinline__ unsigned int f2bf2(float a, float b) {
    union { __hip_bfloat162 h; unsigned int u; } c;
    c.h = __float22bfloat162_rn(make_float2(a, b));
    return c.u;
}
// async global->LDS DMA, 16 B per lane, dest = wave-uniform base + lane*16
static __device__ __forceinline__ void async16(const void* g, void* l) {
    __builtin_amdgcn_global_load_lds(
        (const __attribute__((address_space(1))) void*)g,
        (__attribute__((address_space(3))) void*)l, 16, 0, 0);
}

// ---------- Kernel 1: Vp = relu(h_p @ Wv^T + b)  (r10-proven) ----------------
__global__ __launch_bounds__(256, 4) void proj_v_kernel(
    const float* __restrict__ X,
    const float* __restrict__ Wv,
    const float* __restrict__ bias,
    unsigned short* __restrict__ Y,
    unsigned short* __restrict__ YT)
{
    __shared__ __align__(16) unsigned short Ws[128 * 136];   // 34816 B, reused
    unsigned short* Ys = Ws;            // 64*128 shorts
    unsigned short* Ts = Ws + 8192;     // 128*72 shorts
    const int t = threadIdx.x;
    const int lane = t & 63;
    const int wave = t >> 6;
    const int n16 = lane & 15, q = lane >> 4;
    const long row0 = (long)blockIdx.x * 64;

    // X loads FIRST (latency overlaps W staging below)
    float4 xv[8];
    {
        const float* xrow = X + (row0 + wave * 16 + n16) * DD + q * 8;
        #pragma unroll
        for (int kk = 0; kk < 4; ++kk) {
            xv[2 * kk]     = *(const float4*)(xrow + kk * 32);
            xv[2 * kk + 1] = *(const float4*)(xrow + kk * 32 + 4);
        }
    }

    // stage Wv fp32 -> bf16 into padded LDS
    {
        const float4* Wg = (const float4*)Wv;
        #pragma unroll
        for (int i = 0; i < 16; ++i) {
            int idx = i * 256 + t;            // 4096 float4
            float4 v = Wg[idx];
            int off = idx * 4;                // shorts
            uint2 u = { f2bf2(v.x, v.y), f2bf2(v.z, v.w) };
            *(uint2*)&Ws[(off >> 7) * 136 + (off & 127)] = u;
        }
    }
    __syncthreads();

    f32x4 acc[8];
    #pragma unroll
    for (int j = 0; j < 8; ++j) acc[j] = {0.f, 0.f, 0.f, 0.f};

    #pragma unroll
    for (int kk = 0; kk < 4; ++kk) {
        float4 x0 = xv[2 * kk], x1 = xv[2 * kk + 1];
        union { bf16x8 v; unsigned int u[4]; } a;
        a.u[0] = f2bf2(x0.x, x0.y); a.u[1] = f2bf2(x0.z, x0.w);
        a.u[2] = f2bf2(x1.x, x1.y); a.u[3] = f2bf2(x1.z, x1.w);
        #pragma unroll
        for (int j = 0; j < 8; ++j) {
            bf16x8 b = *(const bf16x8*)&Ws[(j * 16 + n16) * 136 + q * 8 + kk * 32];
            acc[j] = __builtin_amdgcn_mfma_f32_16x16x32_bf16(a.v, b, acc[j], 0, 0, 0);
        }
    }

    unsigned short yb[8][4];
    #pragma unroll
    for (int j = 0; j < 8; ++j) {
        const float bv = bias[j * 16 + n16];
        float y[4];
        #pragma unroll
        for (int r = 0; r < 4; ++r) {
            float v = acc[j][r] + bv;
            y[r] = v > 0.f ? v : 0.f;
        }
        uint2 u = { f2bf2(y[0], y[1]), f2bf2(y[2], y[3]) };
        *(uint2*)&yb[j][0] = u;
    }
    __syncthreads();   // Ws reads done; reuse as Ys/Ts

    #pragma unroll
    for (int j = 0; j < 8; ++j) {
        const int e = j * 16 + n16;
        #pragma unroll
        for (int r = 0; r < 4; ++r)
            Ys[(wave * 16 + q * 4 + r) * 128 + e] = yb[j][r];
        *(uint2*)&Ts[e * 72 + wave * 16 + q * 4] = *(uint2*)&yb[j][0];
    }
    __syncthreads();

    {
        uint4* dstY = (uint4*)(Y + row0 * DD);
        const long b = row0 >> 10;
        const long mt = (row0 & 1023) >> 6;
        uint4* dstT = (uint4*)(YT + ((b * 16 + mt) * 128) * 64);
        #pragma unroll
        for (int i = 0; i < 4; ++i) {
            int idx = i * 256 + t;
            dstY[idx] = ((const uint4*)Ys)[idx];
            int e = idx >> 3, m = (idx & 7) * 8;
            dstT[idx] = *(const uint4*)&Ts[e * 72 + m];
        }
    }
}

// ---------- Kernel 2: fused proj_c + flash attention, 1 barrier/mt -----------
// Grid 512 = (b, nt); 4 waves x 16 n (n-split: wave-private Ps => no P-exchange
// barrier). Phase 1: r10-proven Uc (Ucs pre-scaled by log2 e). Flash loop:
// DMA double-buffer (XOR swizzle); DMA for mt+1 issued at TOP of iteration so
// the single end-of-iteration barrier's vmcnt drain is covered by the whole
// body (QK+exp+PV), not just PV.
__global__ __launch_bounds__(256, 2) void attn_kernel(
    const float* __restrict__ hc,             // (B*512,128) fp32
    const float* __restrict__ Wu,             // (128,128) fp32
    const float* __restrict__ Ub,             // (128) fp32
    const unsigned short* __restrict__ Vp,    // (B,16,64,128) bf16 tiled
    const unsigned short* __restrict__ VpT,   // (B,16,128,64) bf16 tiled
    float* __restrict__ part)                 // (B*8,128) fp32
{
    // shorts: VsA[0,8192) VTsA[8192,16384) VsB[16384,24576) VTsB[24576,32768)
    //         Ps[32768,37376).  Phase1 alias: Ws[0,17408) Ucs[17408,26112).
    __shared__ __align__(16) unsigned short smem[37376];
    unsigned short* Ws  = smem;
    unsigned short* Ucs = smem + 17408;
    unsigned short* Ps  = smem + 32768;

    const int t = threadIdx.x;
    const int lane = t & 63;
    const int wave = t >> 6;
    const int n16 = lane & 15, q = lane >> 4;

    const int id = blockIdx.x;
    const int xcd = id & 7;
    const int slot = id >> 3;
    const int b = xcd * 8 + (slot >> 3);
    const int nt = slot & 7;

    const unsigned short* vpb = Vp + (long)b * MM * DD;    // 16 tiles of 8192
    const unsigned short* vtb = VpT + (long)b * MM * DD;

    const float LOG2E = 1.44269504088896f;

    // ---- Phase 1: Uc for this block's 64 n-rows (r10-proven, no hoist) ----
    {
        const float4* Wg = (const float4*)Wu;
        #pragma unroll
        for (int i = 0; i < 16; ++i) {
            int idx = i * 256 + t;
            float4 v = Wg[idx];
            int off = idx * 4;
            uint2 u = { f2bf2(v.x, v.y), f2bf2(v.z, v.w) };
            *(uint2*)&Ws[(off >> 7) * 136 + (off & 127)] = u;
        }
    }
    __syncthreads();

    f32x4 acc[8];
    #pragma unroll
    for (int j = 0; j < 8; ++j) acc[j] = {0.f, 0.f, 0.f, 0.f};
    {
        const float* xrow = hc + ((long)b * NN + nt * 64 + wave * 16 + n16) * DD + q * 8;
        #pragma unroll
        for (int kk = 0; kk < 4; ++kk) {
            float4 x0 = *(const float4*)(xrow + kk * 32);
            float4 x1 = *(const float4*)(xrow + kk * 32 + 4);
            union { bf16x8 v; unsigned int u[4]; } a;
            a.u[0] = f2bf2(x0.x, x0.y); a.u[1] = f2bf2(x0.z, x0.w);
            a.u[2] = f2bf2(x1.x, x1.y); a.u[3] = f2bf2(x1.z, x1.w);
            #pragma unroll
            for (int j = 0; j < 8; ++j) {
                bf16x8 bb = *(const bf16x8*)&Ws[(j * 16 + n16) * 136 + q * 8 + kk * 32];
                acc[j] = __builtin_amdgcn_mfma_f32_16x16x32_bf16(a.v, bb, acc[j], 0, 0, 0);
            }
        }
    }
    float ucred[8];
    #pragma unroll
    for (int j = 0; j < 8; ++j) {
        const float bv = Ub[j * 16 + n16];
        float s = 0.f;
        #pragma unroll
        for (int r = 0; r < 4; ++r) {
            float v = acc[j][r] + bv;
            v = v > 0.f ? v : 0.f;
            s += v;
            // store Uc * log2(e): QK output feeds exp2 directly
            Ucs[(wave * 16 + q * 4 + r) * 136 + j * 16 + n16] = f2bf(v * LOG2E);
        }
        ucred[j] = s;
    }
    __syncthreads();                                    // sync#2: Ucs ready, Ws dead

    // This wave's OWN 16 n-rows as QK B-frags (n-split, r5/r9-proven)
    bf16x8 Bg[4];
    #pragma unroll
    for (int kk = 0; kk < 4; ++kk)
        Bg[kk] = *(const bf16x8*)&Ucs[(wave * 16 + n16) * 136 + q * 8 + kk * 32];

    // DMA tile 0 into buffer A (Ws region — dead after sync#2).
    // Swizzle: chunk slot L -> row r, slot-col sc; data col c = sc ^ (r & 7).
    {
        #pragma unroll
        for (int i = 0; i < 4; ++i) {          // Vs: 1024 chunks (64 rows x 16)
            int L = wave * 256 + i * 64 + lane;
            int r = L >> 4, sc = L & 15, c = sc ^ (r & 7);
            async16(vpb + r * 128 + c * 8, smem + wave * 2048 + i * 512);
        }
        #pragma unroll
        for (int i = 0; i < 4; ++i) {          // VTs: 1024 chunks (128 rows x 8)
            int L = wave * 256 + i * 64 + lane;
            int r = L >> 3, sc = L & 7, c = sc ^ (r & 7);
            async16(vtb + r * 64 + c * 8, smem + 8192 + wave * 2048 + i * 512);
        }
    }
    __syncthreads();                                    // sync#3: Bg read done, DMA0 landed

    f32x4 O[8];
    #pragma unroll
    for (int j = 0; j < 8; ++j) O[j] = {0.f, 0.f, 0.f, 0.f};
    float lpart = 0.f;

    for (int mt = 0; mt < 16; ++mt) {
        const unsigned short* Vs  = smem + ((mt & 1) ? 16384 : 0);
        const unsigned short* VTs = Vs + 8192;
        unsigned short* nVs = smem + ((mt & 1) ? 0 : 16384);

        // DMA for mt+1 issued FIRST: covered by the whole iteration body.
        // (Previous iteration's end barrier ordered all reads of nVs.)
        if (mt < 15) {
            const unsigned short* sv = vpb + (mt + 1) * 8192;
            const unsigned short* st = vtb + (mt + 1) * 8192;
            #pragma unroll
            for (int i = 0; i < 4; ++i) {
                int L = wave * 256 + i * 64 + lane;
                int r = L >> 4, sc = L & 15, c = sc ^ (r & 7);
                async16(sv + r * 128 + c * 8, nVs + wave * 2048 + i * 512);
            }
            #pragma unroll
            for (int i = 0; i < 4; ++i) {
                int L = wave * 256 + i * 64 + lane;
                int r = L >> 3, sc = L & 7, c = sc ^ (r & 7);
                async16(st + r * 64 + c * 8, nVs + 8192 + wave * 2048 + i * 512);
            }
        }

        // QK (n-split): S[j] reg r -> m = j*16 + q*4 + r, n = wave*16 + n16
        f32x4 S[4];
        #pragma unroll
        for (int j = 0; j < 4; ++j) S[j] = {0.f, 0.f, 0.f, 0.f};
        #pragma unroll
        for (int kk = 0; kk < 4; ++kk) {
            #pragma unroll
            for (int j = 0; j < 4; ++j) {
                int row = j * 16 + n16;
                int col = ((kk * 4 + q) ^ (n16 & 7)) * 8;
                bf16x8 a = *(const bf16x8*)&Vs[row * 128 + col];
                S[j] = __builtin_amdgcn_mfma_f32_16x16x32_bf16(a, Bg[kk], S[j], 0, 0, 0);
            }
        }

        // p = exp2(S) (Uc pre-scaled); Ps wave-private (no exchange barrier)
        #pragma unroll
        for (int j = 0; j < 4; ++j) {
            float p0 = __builtin_exp2f(S[j][0]);
            float p1 = __builtin_exp2f(S[j][1]);
            float p2 = __builtin_exp2f(S[j][2]);
            float p3 = __builtin_exp2f(S[j][3]);
            lpart += (p0 + p1) + (p2 + p3);
            uint2 u = { f2bf2(p0, p1), f2bf2(p2, p3) };
            *(uint2*)&Ps[wave * 1152 + n16 * 72 + j * 16 + q * 4] = u;
        }

        // PV: A = Ps rows (own n, k=m), B = VTs rows (d, k=m)
        #pragma unroll
        for (int kk = 0; kk < 2; ++kk) {
            bf16x8 a = *(const bf16x8*)&Ps[wave * 1152 + n16 * 72 + kk * 32 + q * 8];
            #pragma unroll
            for (int j = 0; j < 8; ++j) {
                int row = j * 16 + n16;
                int col = ((kk * 4 + q) ^ (n16 & 7)) * 8;
                bf16x8 bb = *(const bf16x8*)&VTs[row * 64 + col];
                O[j] = __builtin_amdgcn_mfma_f32_16x16x32_bf16(a, bb, O[j], 0, 0, 0);
            }
        }
        __syncthreads();   // single barrier: drains mt+1 DMA (full-body coverage)
                           // + orders this buffer's reads before its next overwrite
    }

    // ---- epilogue (r9-proven): l per own-n via shuffles, cross-wave reduce ----
    lpart += __shfl_xor(lpart, 16);
    lpart += __shfl_xor(lpart, 32);

    float inv[4];
    #pragma unroll
    for (int r = 0; r < 4; ++r)
        inv[r] = 1.0f / __shfl(lpart, q * 4 + r);

    float* red = (float*)Ps;    // 512 floats; all Ps reads done at final barrier
    #pragma unroll
    for (int j = 0; j < 8; ++j) {
        float s = ucred[j]
                + O[j][0] * inv[0] + O[j][1] * inv[1]
                + O[j][2] * inv[2] + O[j][3] * inv[3];
        s += __shfl_xor(s, 16);
        s += __shfl_xor(s, 32);
        if (q == 0)
            red[wave * 128 + j * 16 + n16] = s;
    }
    __syncthreads();
    if (t < 128) {
        float tot = red[t] + red[128 + t] + red[256 + t] + red[384 + t];
        part[(long)(b * 8 + nt) * DD + t] = tot;
    }
}

// ---------- Kernel 3: out[b][d] = (Sigma_nt part) * q[d] / N -----------------
__global__ __launch_bounds__(256) void finalize_kernel(
    const float* __restrict__ part, const float* __restrict__ qv,
    float* __restrict__ out)
{
    int i = blockIdx.x * 256 + threadIdx.x;     // 8192
    int b = i >> 7, d = i & 127;
    const float* p = part + (long)b * 8 * DD + d;
    float s = 0.f;
    #pragma unroll
    for (int nt = 0; nt < 8; ++nt) s += p[nt * DD];
    out[i] = s * qv[d] * (1.0f / (float)NN);
}

extern "C" void kernel_launch(void* const* d_in, const int* in_sizes, int n_in,
                              void* d_out, int out_size, void* d_ws, size_t ws_size,
                              hipStream_t stream) {
    const float* h_c = (const float*)d_in[0];
    const float* h_p = (const float*)d_in[1];
    const float* U_w = (const float*)d_in[2];
    const float* U_b = (const float*)d_in[3];
    const float* V_w = (const float*)d_in[4];
    const float* V_b = (const float*)d_in[5];
    const float* qv  = (const float*)d_in[6];
    float* out = (float*)d_out;

    unsigned short* Vp  = (unsigned short*)d_ws;                 // (B,16,64,128) bf16
    unsigned short* VpT = Vp + (size_t)BB * MM * DD;             // (B,16,128,64) bf16
    float* part = (float*)(VpT + (size_t)BB * MM * DD);          // (B*8,128) fp32

    proj_v_kernel<<<BB * MM / 64, 256, 0, stream>>>(h_p, V_w, V_b, Vp, VpT);
    attn_kernel<<<512, 256, 0, stream>>>(h_c, U_w, U_b, Vp, VpT, part);
    finalize_kernel<<<32, 256, 0, stream>>>(part, qv, out);
}